// Round 10
// baseline (68.279 us; speedup 1.0000x reference)
//
#include <hip/hip_runtime.h>
#include <hip/hip_bf16.h>
#include <stdint.h>

typedef __attribute__((ext_vector_type(4))) float f32x4;
typedef __attribute__((ext_vector_type(8))) _Float16 f16x8;
typedef __attribute__((ext_vector_type(4))) _Float16 f16x4;
typedef __attribute__((ext_vector_type(2))) __fp16 fp16x2;

#define NB 32
#define MM 1024
#define DD 128
#define BKV 32
#define HTILE 16           // tiles per kv-half: 512/32
#define LOG2E 1.44269504089f
#define RTHR 6.0f

static constexpr size_t ARR = (size_t)NB * MM * DD;  // elems per f16 array

// ws layout (f16): Ah @0, Bh @ARR, VA32 @2*ARR, VB32 @3*ARR
// Row-major Xh[b][r][128]: 16B chunk c of row r at in-row byte (c*16) ^ ((r&7)<<4)
// V32 (BKV=32-native V^T tiles): [b][T=kv>>5][d][32kv], tile = 8KB contiguous.
//   Within a tile, stored position q holds original kv 32T + pi(q),
//   pi(q) = q2*16 + q4*8 + q3*4 + (q&3)  — chosen so PV's B-operand P-fragment
//   is the in-register sc values: pf[j] = sc[j>>2][j&3] (no cross-lane moves).

__device__ __forceinline__ float fexp2(float x) { return __builtin_amdgcn_exp2f(x); }

__device__ __forceinline__ void gl16(const void* g, void* l) {
  __builtin_amdgcn_global_load_lds((const __attribute__((address_space(1))) void*)g,
                                   (__attribute__((address_space(3))) void*)l, 16, 0, 0);
}

__global__ __launch_bounds__(256) void prep_kernel(const float* __restrict__ A,
                                                   const float* __restrict__ B,
                                                   _Float16* __restrict__ ws) {
  const int rt = blockIdx.x;     // 64-kv tile
  const int b  = blockIdx.y;
  const int wh = blockIdx.z;     // 0=A, 1=B
  const float* __restrict__ src = wh ? B : A;
  _Float16* __restrict__ Xh  = ws + (size_t)wh * ARR;
  _Float16* __restrict__ V32 = ws + 2 * ARR + (size_t)wh * ARR;

  __shared__ __align__(16) _Float16 tile[64][130];
  const int t = threadIdx.x;

  // phase 1: f32 -> f16, row-major swizzled write + LDS stash
#pragma unroll
  for (int it = 0; it < 4; ++it) {
    int id  = it * 256 + t;
    int row = id >> 4;
    int ch  = id & 15;
    int grow = rt * 64 + row;
    const float* p = src + ((size_t)(b * MM + grow) * DD + ch * 8);
    float4 x0 = *(const float4*)p;
    float4 x1 = *(const float4*)(p + 4);
    f16x8 h;
    h[0] = (_Float16)x0.x; h[1] = (_Float16)x0.y; h[2] = (_Float16)x0.z; h[3] = (_Float16)x0.w;
    h[4] = (_Float16)x1.x; h[5] = (_Float16)x1.y; h[6] = (_Float16)x1.z; h[7] = (_Float16)x1.w;
    char* dst = (char*)Xh + (((size_t)(b * MM + grow)) << 8) + ((ch << 4) ^ ((row & 7) << 4));
    *(f16x8*)dst = h;
#pragma unroll
    for (int j = 0; j < 8; ++j) tile[row][ch * 8 + j] = h[j];
  }
  __syncthreads();

  // phase 2: V32 tiles. Thread (d, ch) covers original kvs rt*64 + ch*8 + j.
  // r = kv&31 = (ch&3)*8 + j;  q = pi^{-1}(r) = 16*r3 + 8*r2 + 4*r4 + (r&3)
  //   -> j=0..3 land at q = 16*cb0 + 4*cb1 + j     (cb = ch&3)
  //      j=4..7 land at q = that + 8
#pragma unroll
  for (int it = 0; it < 4; ++it) {
    int id = it * 256 + t;
    int d  = id >> 3;               // 0..127
    int ch = id & 7;                // 0..7
    f16x4 lo, hi;
#pragma unroll
    for (int j = 0; j < 4; ++j) lo[j] = tile[ch * 8 + j][d];
#pragma unroll
    for (int j = 0; j < 4; ++j) hi[j] = tile[ch * 8 + 4 + j][d];
    int T  = rt * 2 + (ch >> 2);
    int cb = ch & 3;
    char* dst = (char*)V32 + (((size_t)(b * 32 + T)) << 13) + d * 64
              + 32 * (cb & 1) + 8 * (cb >> 1);
    *(f16x4*)dst = lo;
    *(f16x4*)(dst + 16) = hi;
  }
}

union SMem {
  char stage[2][2][16384];          // [half][buf][ K 8KB | V 8KB ] = 64 KB
  struct {
    float O1[128][132];             // half-1 unnormalized O
    float m1[128];
    float l1[128];
  } mrg;                            // ~68.6 KB
};

__global__ __launch_bounds__(512, 2) void attn_kernel(const _Float16* __restrict__ ws,
                                                      float* __restrict__ out) {
  // XCD-aware decomposition: blocks with same (b,dir) share g%8 -> same XCD
  const int g   = blockIdx.x;           // 0..511
  const int x   = g & 7;
  const int t2  = g >> 3;
  const int qt  = t2 & 7;               // 0..7 (128-row Q tile)
  const int p   = ((t2 >> 3) << 3) | x; // 0..63 = b + 32*dir
  const int b   = p & 31;
  const int dir = p >> 5;

  const _Float16* __restrict__ Qh  = ws + (dir ? ARR : 0);
  const _Float16* __restrict__ Kh  = ws + (dir ? 0 : ARR);
  const _Float16* __restrict__ V32 = ws + 2 * ARR + (dir ? 0 : ARR);
  float* __restrict__ outp = out + (size_t)dir * ARR;

  __shared__ __align__(16) SMem sm;

  const int tid  = threadIdx.x;        // 0..511
  const int w    = tid >> 6;           // 0..7
  const int half = w >> 2;             // 0: kv 0..511, 1: kv 512..1023
  const int ht   = tid & 255;          // thread within half
  const int lane = tid & 63;
  const int lrow = lane & 15;
  const int lgrp = lane >> 4;

  const int qloc = (w & 3) * 32 + lrow;     // block-local q (qb adds 16)
  const int q0   = qt * 128 + qloc;         // global q row

  // ---- Q B-fragments (both q-blocks)
  f16x8 qf[2][4];
  {
    const int swz = (lrow & 7) << 4;
#pragma unroll
    for (int qb = 0; qb < 2; ++qb) {
      const char* qbase = (const char*)Qh + (((size_t)(b * MM + q0 + qb * 16)) << 8);
#pragma unroll
      for (int kc = 0; kc < 4; ++kc)
        qf[qb][kc] = *(const f16x8*)(qbase + ((kc * 64 + lgrp * 16) ^ swz));
    }
  }

  // ---- per-lane K LDS offsets (swizzle folded; kc parity split); rows 0..31
  const int pl  = (lgrp * 16) ^ ((lrow & 3) << 4);
  const int lb6 = (lrow & 4) << 4;
  const int kE = lrow * 256 + pl + lb6;          // kc even
  const int kO = lrow * 256 + pl + (64 - lb6);   // kc odd
  // ---- V LDS read base (dense [d][32] rows; no swizzle needed)
  const int vb = 8192 + lrow * 64 + lgrp * 16;

  // ---- staging source bases (per thread-in-half)
  const char* ksrc = (const char*)Kh + (((size_t)(b * MM + half * 512)) << 8) + (size_t)ht * 16;
  const char* vsrc = (const char*)V32 + (((size_t)(b * 32 + half * 16)) << 13) + (size_t)ht * 16;

  f32x4 oacc[2][8];
#pragma unroll
  for (int qb = 0; qb < 2; ++qb)
#pragma unroll
    for (int dt = 0; dt < 8; ++dt) oacc[qb][dt] = (f32x4)0.0f;
  float mrun[2] = {-1e30f, -1e30f};
  float lrun[2] = {0.0f, 0.0f};

  // prologue: stage tile 0 of this half
  {
    char* sb = sm.stage[half][0];
    gl16(ksrc, sb + ht * 16);
    gl16(ksrc + 4096, sb + 4096 + ht * 16);
    gl16(vsrc, sb + 8192 + ht * 16);
    gl16(vsrc + 4096, sb + 12288 + ht * 16);
  }
  asm volatile("s_waitcnt vmcnt(0)" ::: "memory");
  __syncthreads();

#pragma unroll 1
  for (int t = 0; t < HTILE; ++t) {
    const char* base = sm.stage[half][t & 1];

    // 1. issue next tile's staging (hidden under compute)
    if (t + 1 < HTILE) {
      char* sb = sm.stage[half][(t + 1) & 1];
      const char* kp = ksrc + (size_t)(t + 1) * 8192;
      const char* vp = vsrc + (size_t)(t + 1) * 8192;
      gl16(kp, sb + ht * 16);
      gl16(kp + 4096, sb + 4096 + ht * 16);
      gl16(vp, sb + 8192 + ht * 16);
      gl16(vp + 4096, sb + 12288 + ht * 16);
    }

    // 2. S^T = mfma(K, Q): rows kv (lgrp*4+r +16nt), col q = lrow
    f32x4 sc[2][2];
#pragma unroll
    for (int qb = 0; qb < 2; ++qb)
#pragma unroll
      for (int nt = 0; nt < 2; ++nt) sc[qb][nt] = (f32x4)0.0f;
#pragma unroll
    for (int nt = 0; nt < 2; ++nt) {
#pragma unroll
      for (int kc = 0; kc < 4; ++kc) {
        const int off = ((kc & 1) ? kO + (kc - 1) * 64 : kE + kc * 64) + nt * 4096;
        f16x8 kf = *(const f16x8*)(base + off);
        sc[0][nt] = __builtin_amdgcn_mfma_f32_16x16x32_f16(kf, qf[0][kc], sc[0][nt], 0, 0, 0);
        sc[1][nt] = __builtin_amdgcn_mfma_f32_16x16x32_f16(kf, qf[1][kc], sc[1][nt], 0, 0, 0);
      }
    }

    // 3. V(t) LDS -> registers (dense rows; latency hides under softmax VALU)
    f16x8 vreg[8];
#pragma unroll
    for (int dt = 0; dt < 8; ++dt)
      vreg[dt] = *(const f16x8*)(base + vb + dt * 1024);

    // 4. softmax: in-lane max check; cross-lane only on rare trigger
    float mx[2];
#pragma unroll
    for (int qb = 0; qb < 2; ++qb) {
      float a0 = fmaxf(fmaxf(sc[qb][0][0], sc[qb][0][1]), fmaxf(sc[qb][0][2], sc[qb][0][3]));
      float a1 = fmaxf(fmaxf(sc[qb][1][0], sc[qb][1][1]), fmaxf(sc[qb][1][2], sc[qb][1][3]));
      mx[qb] = fmaxf(a0, a1);
    }
    bool need = (mx[0] > mrun[0] + RTHR) || (mx[1] > mrun[1] + RTHR);
    if (__any(need)) {
#pragma unroll
      for (int qb = 0; qb < 2; ++qb) {
        float cm = mx[qb];
        cm = fmaxf(cm, __shfl_xor(cm, 16));
        cm = fmaxf(cm, __shfl_xor(cm, 32));
        float mnew = fmaxf(mrun[qb], cm);
        float scale = fexp2((mrun[qb] - mnew) * LOG2E);
        lrun[qb] *= scale;
#pragma unroll
        for (int dt = 0; dt < 8; ++dt) oacc[qb][dt] *= scale;
        mrun[qb] = mnew;
      }
    }

    // 5. P = exp(S-m) in-lane, pack: pf[j] = sc[j>>2][j&3] (pi-aligned)
    f16x8 pf[2];
#pragma unroll
    for (int qb = 0; qb < 2; ++qb) {
      union { fp16x2 h[4]; f16x8 v; } u;
      const float nml = -mrun[qb] * LOG2E;
      float e00 = fexp2(fmaf(sc[qb][0][0], LOG2E, nml));
      float e01 = fexp2(fmaf(sc[qb][0][1], LOG2E, nml));
      float e02 = fexp2(fmaf(sc[qb][0][2], LOG2E, nml));
      float e03 = fexp2(fmaf(sc[qb][0][3], LOG2E, nml));
      float e10 = fexp2(fmaf(sc[qb][1][0], LOG2E, nml));
      float e11 = fexp2(fmaf(sc[qb][1][1], LOG2E, nml));
      float e12 = fexp2(fmaf(sc[qb][1][2], LOG2E, nml));
      float e13 = fexp2(fmaf(sc[qb][1][3], LOG2E, nml));
      lrun[qb] += ((e00 + e01) + (e02 + e03)) + ((e10 + e11) + (e12 + e13));
      u.h[0] = __builtin_amdgcn_cvt_pkrtz(e00, e01);
      u.h[1] = __builtin_amdgcn_cvt_pkrtz(e02, e03);
      u.h[2] = __builtin_amdgcn_cvt_pkrtz(e10, e11);
      u.h[3] = __builtin_amdgcn_cvt_pkrtz(e12, e13);
      pf[qb] = u.v;
    }

    // 6. PV: O^T += mfma(V^T, P^T)
#pragma unroll
    for (int dt = 0; dt < 8; ++dt) {
      oacc[0][dt] = __builtin_amdgcn_mfma_f32_16x16x32_f16(vreg[dt], pf[0], oacc[0][dt], 0, 0, 0);
      oacc[1][dt] = __builtin_amdgcn_mfma_f32_16x16x32_f16(vreg[dt], pf[1], oacc[1][dt], 0, 0, 0);
    }

    // 7. drain staging + barrier
    asm volatile("s_waitcnt vmcnt(0)" ::: "memory");
    __syncthreads();
  }

  // ---- combine per-lane l across lgrp (within this half)
  float lsum[2];
#pragma unroll
  for (int qb = 0; qb < 2; ++qb) {
    float l = lrun[qb];
    l += __shfl_xor(l, 16);
    l += __shfl_xor(l, 32);
    lsum[qb] = l;
  }

  // ---- half 1 publishes unnormalized O, m, l (stage area is dead after last barrier)
  if (half == 1) {
#pragma unroll
    for (int qb = 0; qb < 2; ++qb) {
      const int qr = qloc + qb * 16;
#pragma unroll
      for (int dt = 0; dt < 8; ++dt)
        *(f32x4*)&sm.mrg.O1[qr][lgrp * 4 + dt * 16] = oacc[qb][dt];
      if (lgrp == 0) {
        sm.mrg.m1[qr] = mrun[qb];
        sm.mrg.l1[qr] = lsum[qb];
      }
    }
  }
  __syncthreads();

  // ---- half 0 merges and stores
  if (half == 0) {
#pragma unroll
    for (int qb = 0; qb < 2; ++qb) {
      const int qr = qloc + qb * 16;
      float m1v = sm.mrg.m1[qr];
      float l1v = sm.mrg.l1[qr];
      float m  = fmaxf(mrun[qb], m1v);
      float a0 = fexp2((mrun[qb] - m) * LOG2E);
      float a1 = fexp2((m1v - m) * LOG2E);
      float inv = __builtin_amdgcn_rcpf(lsum[qb] * a0 + l1v * a1);
      float* op = outp + ((size_t)(b * MM + q0 + qb * 16)) * DD + lgrp * 4;
#pragma unroll
      for (int dt = 0; dt < 8; ++dt) {
        f32x4 o1 = *(const f32x4*)&sm.mrg.O1[qr][lgrp * 4 + dt * 16];
        f32x4 v = (oacc[qb][dt] * a0 + o1 * a1) * inv;
        *(f32x4*)(op + dt * 16) = v;
      }
    }
  }
}

extern "C" void kernel_launch(void* const* d_in, const int* in_sizes, int n_in,
                              void* d_out, int out_size, void* d_ws, size_t ws_size,
                              hipStream_t stream) {
  const float* A = (const float*)d_in[0];
  const float* B = (const float*)d_in[1];
  float* out = (float*)d_out;
  if (ws_size < 4 * ARR * sizeof(_Float16)) return;  // need 33.6 MB scratch
  _Float16* ws = (_Float16*)d_ws;

  dim3 g1(16, 32, 2);
  prep_kernel<<<g1, dim3(256, 1, 1), 0, stream>>>(A, B, ws);
  dim3 g2(512, 1, 1);
  attn_kernel<<<g2, dim3(512, 1, 1), 0, stream>>>(ws, out);
}

// Round 11
// 67.738 us; speedup vs baseline: 1.0080x; 1.0080x over previous
//
#include <hip/hip_runtime.h>
#include <hip/hip_bf16.h>
#include <stdint.h>

typedef __attribute__((ext_vector_type(4))) float f32x4;
typedef __attribute__((ext_vector_type(8))) _Float16 f16x8;
typedef __attribute__((ext_vector_type(4))) _Float16 f16x4;
typedef __attribute__((ext_vector_type(2))) __fp16 fp16x2;

#define NB 32
#define MM 1024
#define DD 128
#define BKV 64
#define HTILE 8            // tiles per kv-half: 512/64
#define LOG2E 1.44269504089f
#define RTHR 6.0f

static constexpr size_t ARR = (size_t)NB * MM * DD;  // elems per f16 array

// ws layout (f16): Ah @0, Bh @ARR, ATh @2*ARR, BTh @3*ARR
// Row-major Xh[b][r][128]: 16B chunk c of row r at in-row byte (c*16) ^ ((r&7)<<4)
// Transposed XTh[b][d][1024]: per 64-kv (128B) window, chunk c at (c*16) ^ ((d&7)<<4),
//   kv positions sigma_V-permuted (prep phase 2).

__device__ __forceinline__ float fexp2(float x) { return __builtin_amdgcn_exp2f(x); }

__global__ __launch_bounds__(256) void prep_kernel(const float* __restrict__ A,
                                                   const float* __restrict__ B,
                                                   _Float16* __restrict__ ws) {
  const int rt = blockIdx.x;     // 64-row tile
  const int b  = blockIdx.y;
  const int wh = blockIdx.z;     // 0=A, 1=B
  const float* __restrict__ src = wh ? B : A;
  _Float16* __restrict__ Xh  = ws + (size_t)wh * ARR;
  _Float16* __restrict__ XTh = ws + 2 * ARR + (size_t)wh * ARR;

  __shared__ __align__(16) _Float16 tile[64][130];
  const int t = threadIdx.x;

  // phase 1: f32 -> f16, row-major swizzled write + LDS stash
#pragma unroll
  for (int it = 0; it < 4; ++it) {
    int id  = it * 256 + t;          // 0..1023 (16B chunks)
    int row = id >> 4;               // 0..63
    int ch  = id & 15;
    int grow = rt * 64 + row;
    const float* p = src + ((size_t)(b * MM + grow) * DD + ch * 8);
    float4 x0 = *(const float4*)p;
    float4 x1 = *(const float4*)(p + 4);
    f16x8 h;
    h[0] = (_Float16)x0.x; h[1] = (_Float16)x0.y; h[2] = (_Float16)x0.z; h[3] = (_Float16)x0.w;
    h[4] = (_Float16)x1.x; h[5] = (_Float16)x1.y; h[6] = (_Float16)x1.z; h[7] = (_Float16)x1.w;
    char* dst = (char*)Xh + (((size_t)(b * MM + grow)) << 8) + ((ch << 4) ^ ((row & 7) << 4));
    *(f16x8*)dst = h;
#pragma unroll
    for (int j = 0; j < 8; ++j) tile[row][ch * 8 + j] = h[j];
  }
  __syncthreads();

  // phase 2: transposed, sigma_V-permuted, swizzled write.
  // sigma_V(i): out5=i5, out4=i2, out3=i4, out2=i3, out1:0=i1:0
#pragma unroll
  for (int it = 0; it < 4; ++it) {
    int id = it * 256 + t;           // 0..1023
    int d  = id >> 3;                // 0..127
    int ch = id & 7;                 // 16B chunk within this tile's 64-kv window
    f16x8 h;
#pragma unroll
    for (int j = 0; j < 8; ++j) {
      int i = ch * 8 + j;
      int s = (i & 0x23) | ((i & 4) << 2) | ((i & 24) >> 1);
      h[j] = tile[s][d];
    }
    char* dst = (char*)XTh + (((size_t)(b * DD + d)) << 11) + (rt << 7)
              + ((ch << 4) ^ ((d & 7) << 4));
    *(f16x8*)dst = h;
  }
}

union SMem {
  char stage[2][32768];             // [half][ K 16KB | VT 16KB ]  = 64 KB (single buf)
  struct {
    _Float16 O1[128][136];          // half-1 unnormalized O (f16), padded rows
    float m1[128];
    float l1[128];
  } mrg;                            // 35.8 KB, overlays stage after the loop
};

__global__ __launch_bounds__(512, 2) void attn_kernel(const _Float16* __restrict__ ws,
                                                      float* __restrict__ out) {
  // XCD-aware decomposition: blocks with same (b,dir) share g%8 -> same XCD
  const int g   = blockIdx.x;           // 0..511
  const int x   = g & 7;
  const int t2  = g >> 3;
  const int qt  = t2 & 7;               // 0..7 (128-row Q tile)
  const int p   = ((t2 >> 3) << 3) | x; // 0..63 = b + 32*dir
  const int b   = p & 31;
  const int dir = p >> 5;

  const _Float16* __restrict__ Qh  = ws + (dir ? ARR : 0);
  const _Float16* __restrict__ Kh  = ws + (dir ? 0 : ARR);
  const _Float16* __restrict__ VTh = ws + 2 * ARR + (dir ? 0 : ARR);
  float* __restrict__ outp = out + (size_t)dir * ARR;

  __shared__ __align__(16) SMem sm;

  const int tid  = threadIdx.x;        // 0..511
  const int w    = tid >> 6;           // 0..7
  const int half = w >> 2;             // 0: kv 0..511, 1: kv 512..1023
  const int ht   = tid & 255;          // thread within half
  const int lane = tid & 63;
  const int lrow = lane & 15;
  const int lgrp = lane >> 4;

  const int qloc = (w & 3) * 32 + lrow;     // block-local q (qb adds 16)
  const int q0   = qt * 128 + qloc;         // global q row

  // ---- Q B-fragments (both q-blocks)
  f16x8 qf[2][4];
  {
    const int swz = (lrow & 7) << 4;
#pragma unroll
    for (int qb = 0; qb < 2; ++qb) {
      const char* qbase = (const char*)Qh + (((size_t)(b * MM + q0 + qb * 16)) << 8);
#pragma unroll
      for (int kc = 0; kc < 4; ++kc)
        qf[qb][kc] = *(const f16x8*)(qbase + ((kc * 64 + lgrp * 16) ^ swz));
    }
  }

  // ---- per-lane LDS byte offsets within this half's buffer (swizzle folded)
  const int pl  = (lgrp * 16) ^ ((lrow & 3) << 4);
  const int lb6 = (lrow & 4) << 4;
  const int kE = lrow * 256 + pl + lb6;          // K reads, kc even
  const int kO = lrow * 256 + pl + (64 - lb6);   // K reads, kc odd
  const int vE = 16384 + lrow * 128 + pl + lb6;          // VT reads, kc2=0
  const int vO = 16384 + lrow * 128 + pl + (64 - lb6);   // VT reads, kc2=1

  // ---- staging source bases (per thread-in-half; kv offset by half*512)
  const char* ksrc = (const char*)Kh + (((size_t)(b * MM + half * 512)) << 8) + (size_t)ht * 16;
  const char* vsrc = (const char*)VTh + (((size_t)(b * DD)) << 11) + (size_t)half * 1024
                   + ((size_t)(ht >> 3) << 11) + (size_t)(ht & 7) * 16;
  char* lbase = sm.stage[half] + (size_t)ht * 16;

  f32x4 oacc[2][8];
#pragma unroll
  for (int qb = 0; qb < 2; ++qb)
#pragma unroll
    for (int dt = 0; dt < 8; ++dt) oacc[qb][dt] = (f32x4)0.0f;
  float mrun[2] = {-1e30f, -1e30f};
  float lrun[2] = {0.0f, 0.0f};

  f16x8 srK[4], srV[4];   // reg-staged next tile (T14)

  // prologue: tile0 -> regs -> LDS; tile1 -> regs (stays in flight)
#pragma unroll
  for (int it = 0; it < 4; ++it) {
    srK[it] = *(const f16x8*)(ksrc + it * 4096);
    srV[it] = *(const f16x8*)(vsrc + (size_t)it * 65536);
  }
#pragma unroll
  for (int it = 0; it < 4; ++it) {
    *(f16x8*)(lbase + it * 4096) = srK[it];
    *(f16x8*)(lbase + 16384 + it * 4096) = srV[it];
  }
#pragma unroll
  for (int it = 0; it < 4; ++it) {
    srK[it] = *(const f16x8*)(ksrc + 16384 + it * 4096);
    srV[it] = *(const f16x8*)(vsrc + 128 + (size_t)it * 65536);
  }
  __syncthreads();

#pragma unroll 1
  for (int t = 0; t < HTILE; ++t) {
    const char* base = sm.stage[half];

    // ---- S^T = mfma(K, Q): rows kv (lgrp*4+r +16nt), col q = lrow
    f32x4 sc[2][4];
#pragma unroll
    for (int qb = 0; qb < 2; ++qb)
#pragma unroll
      for (int nt = 0; nt < 4; ++nt) sc[qb][nt] = (f32x4)0.0f;
#pragma unroll
    for (int nt = 0; nt < 4; ++nt) {
#pragma unroll
      for (int kc = 0; kc < 4; ++kc) {
        const int off = ((kc & 1) ? kO + (kc - 1) * 64 : kE + kc * 64) + nt * 4096;
        f16x8 kf = *(const f16x8*)(base + off);
        sc[0][nt] = __builtin_amdgcn_mfma_f32_16x16x32_f16(kf, qf[0][kc], sc[0][nt], 0, 0, 0);
        sc[1][nt] = __builtin_amdgcn_mfma_f32_16x16x32_f16(kf, qf[1][kc], sc[1][nt], 0, 0, 0);
      }
    }

    // ---- softmax: in-lane max check; cross-lane only on rare trigger
    float mx[2];
#pragma unroll
    for (int qb = 0; qb < 2; ++qb) {
      float a0 = fmaxf(fmaxf(sc[qb][0][0], sc[qb][0][1]), fmaxf(sc[qb][0][2], sc[qb][0][3]));
      float a1 = fmaxf(fmaxf(sc[qb][1][0], sc[qb][1][1]), fmaxf(sc[qb][1][2], sc[qb][1][3]));
      float a2 = fmaxf(fmaxf(sc[qb][2][0], sc[qb][2][1]), fmaxf(sc[qb][2][2], sc[qb][2][3]));
      float a3 = fmaxf(fmaxf(sc[qb][3][0], sc[qb][3][1]), fmaxf(sc[qb][3][2], sc[qb][3][3]));
      mx[qb] = fmaxf(fmaxf(a0, a1), fmaxf(a2, a3));
    }
    bool need = (mx[0] > mrun[0] + RTHR) || (mx[1] > mrun[1] + RTHR);
    if (__any(need)) {
#pragma unroll
      for (int qb = 0; qb < 2; ++qb) {
        float cm = mx[qb];
        cm = fmaxf(cm, __shfl_xor(cm, 16));
        cm = fmaxf(cm, __shfl_xor(cm, 32));
        float mnew = fmaxf(mrun[qb], cm);
        float scale = fexp2((mrun[qb] - mnew) * LOG2E);
        lrun[qb] *= scale;
#pragma unroll
        for (int dt = 0; dt < 8; ++dt) oacc[qb][dt] *= scale;
        mrun[qb] = mnew;
      }
    }

    // ---- P = exp(S - m) in-lane, pack to f16 B-fragments (sigma_V aligned)
    f16x8 pf[2][2];
#pragma unroll
    for (int qb = 0; qb < 2; ++qb) {
      union { fp16x2 h[8]; f16x8 v[2]; } u;
      float ps = 0.0f;
      const float nml = -mrun[qb] * LOG2E;
#pragma unroll
      for (int nt = 0; nt < 4; ++nt) {
        float p0 = fexp2(fmaf(sc[qb][nt][0], LOG2E, nml));
        float p1 = fexp2(fmaf(sc[qb][nt][1], LOG2E, nml));
        float p2 = fexp2(fmaf(sc[qb][nt][2], LOG2E, nml));
        float p3 = fexp2(fmaf(sc[qb][nt][3], LOG2E, nml));
        ps += (p0 + p1) + (p2 + p3);
        u.h[nt * 2 + 0] = __builtin_amdgcn_cvt_pkrtz(p0, p1);
        u.h[nt * 2 + 1] = __builtin_amdgcn_cvt_pkrtz(p2, p3);
      }
      lrun[qb] += ps;
      pf[qb][0] = u.v[0];
      pf[qb][1] = u.v[1];
    }

    // ---- PV: O^T += mfma(V^T, P^T), V read from LDS inline
#pragma unroll
    for (int dt = 0; dt < 8; ++dt) {
      f16x8 v0 = *(const f16x8*)(base + vE + dt * 2048);
      f16x8 v1 = *(const f16x8*)(base + vO + dt * 2048);
      oacc[0][dt] = __builtin_amdgcn_mfma_f32_16x16x32_f16(v0, pf[0][0], oacc[0][dt], 0, 0, 0);
      oacc[0][dt] = __builtin_amdgcn_mfma_f32_16x16x32_f16(v1, pf[0][1], oacc[0][dt], 0, 0, 0);
      oacc[1][dt] = __builtin_amdgcn_mfma_f32_16x16x32_f16(v0, pf[1][0], oacc[1][dt], 0, 0, 0);
      oacc[1][dt] = __builtin_amdgcn_mfma_f32_16x16x32_f16(v1, pf[1][1], oacc[1][dt], 0, 0, 0);
    }

    __syncthreads();   // all reads of tile t done

    // ---- write tile t+1 (regs loaded a full iteration ago; counted wait only)
    if (t + 1 < HTILE) {
#pragma unroll
      for (int it = 0; it < 4; ++it) {
        *(f16x8*)(lbase + it * 4096) = srK[it];
        *(f16x8*)(lbase + 16384 + it * 4096) = srV[it];
      }
    }
    // ---- issue loads for tile t+2 (land during compute of t+1)
    if (t + 2 < HTILE) {
      const char* kp = ksrc + (size_t)(t + 2) * 16384;
      const char* vp = vsrc + (size_t)(t + 2) * 128;
#pragma unroll
      for (int it = 0; it < 4; ++it) {
        srK[it] = *(const f16x8*)(kp + it * 4096);
        srV[it] = *(const f16x8*)(vp + (size_t)it * 65536);
      }
    }
    __syncthreads();   // tile t+1 visible
  }

  // ---- combine per-lane l across lgrp (within this half)
  float lsum[2];
#pragma unroll
  for (int qb = 0; qb < 2; ++qb) {
    float l = lrun[qb];
    l += __shfl_xor(l, 16);
    l += __shfl_xor(l, 32);
    lsum[qb] = l;
  }

  // ---- half 1 publishes unnormalized O (f16), m, l over the dead stage area
  if (half == 1) {
#pragma unroll
    for (int qb = 0; qb < 2; ++qb) {
      const int qr = qloc + qb * 16;
#pragma unroll
      for (int dt = 0; dt < 8; ++dt) {
        union { fp16x2 h[2]; f16x4 v; } u;
        u.h[0] = __builtin_amdgcn_cvt_pkrtz(oacc[qb][dt][0], oacc[qb][dt][1]);
        u.h[1] = __builtin_amdgcn_cvt_pkrtz(oacc[qb][dt][2], oacc[qb][dt][3]);
        *(f16x4*)&sm.mrg.O1[qr][lgrp * 4 + dt * 16] = u.v;
      }
      if (lgrp == 0) {
        sm.mrg.m1[qr] = mrun[qb];
        sm.mrg.l1[qr] = lsum[qb];
      }
    }
  }
  __syncthreads();

  // ---- half 0 merges and stores
  if (half == 0) {
#pragma unroll
    for (int qb = 0; qb < 2; ++qb) {
      const int qr = qloc + qb * 16;
      float m1v = sm.mrg.m1[qr];
      float l1v = sm.mrg.l1[qr];
      float m  = fmaxf(mrun[qb], m1v);
      float a0 = fexp2((mrun[qb] - m) * LOG2E);
      float a1 = fexp2((m1v - m) * LOG2E);
      float inv = __builtin_amdgcn_rcpf(lsum[qb] * a0 + l1v * a1);
      float ia0 = a0 * inv, ia1 = a1 * inv;
      float* op = outp + ((size_t)(b * MM + q0 + qb * 16)) * DD + lgrp * 4;
#pragma unroll
      for (int dt = 0; dt < 8; ++dt) {
        f16x4 o1h = *(const f16x4*)&sm.mrg.O1[qr][lgrp * 4 + dt * 16];
        f32x4 o1;
        o1[0] = (float)o1h[0]; o1[1] = (float)o1h[1];
        o1[2] = (float)o1h[2]; o1[3] = (float)o1h[3];
        f32x4 v = oacc[qb][dt] * ia0 + o1 * ia1;
        *(f32x4*)(op + dt * 16) = v;
      }
    }
  }
}

extern "C" void kernel_launch(void* const* d_in, const int* in_sizes, int n_in,
                              void* d_out, int out_size, void* d_ws, size_t ws_size,
                              hipStream_t stream) {
  const float* A = (const float*)d_in[0];
  const float* B = (const float*)d_in[1];
  float* out = (float*)d_out;
  if (ws_size < 4 * ARR * sizeof(_Float16)) return;  // need 33.6 MB scratch
  _Float16* ws = (_Float16*)d_ws;

  dim3 g1(16, 32, 2);
  prep_kernel<<<g1, dim3(256, 1, 1), 0, stream>>>(A, B, ws);
  dim3 g2(512, 1, 1);
  attn_kernel<<<g2, dim3(512, 1, 1), 0, stream>>>(ws, out);
}

// Round 12
// 60.446 us; speedup vs baseline: 1.1296x; 1.1206x over previous
//
#include <hip/hip_runtime.h>
#include <hip/hip_bf16.h>
#include <stdint.h>

typedef __attribute__((ext_vector_type(4))) float f32x4;
typedef __attribute__((ext_vector_type(8))) _Float16 f16x8;
typedef __attribute__((ext_vector_type(2))) __fp16 fp16x2;

#define NB 32
#define MM 1024
#define DD 128
#define BKV 64
#define NTILE (MM / BKV)
#define LOG2E 1.44269504089f
#define RTHR 8.0f

static constexpr size_t ARR = (size_t)NB * MM * DD;  // elems per f16 array

// ws layout (f16): Ah @0, Bh @ARR, ATh @2*ARR, BTh @3*ARR
// Row-major Xh[b][r][128]: 16B chunk c of row r at in-row byte (c*16) ^ ((r&7)<<4)
// Transposed XTh[b][d][1024]: per 64-kv (128B) window, chunk c at (c*16) ^ ((d&7)<<4),
//   kv positions sigma_V-permuted (prep phase 2).

__device__ __forceinline__ float fexp2(float x) { return __builtin_amdgcn_exp2f(x); }

__device__ __forceinline__ void gl16(const void* g, void* l) {
  __builtin_amdgcn_global_load_lds((const __attribute__((address_space(1))) void*)g,
                                   (__attribute__((address_space(3))) void*)l, 16, 0, 0);
}

__global__ __launch_bounds__(256) void prep_kernel(const float* __restrict__ A,
                                                   const float* __restrict__ B,
                                                   _Float16* __restrict__ ws) {
  const int rt = blockIdx.x;     // 64-row tile
  const int b  = blockIdx.y;
  const int wh = blockIdx.z;     // 0=A, 1=B
  const float* __restrict__ src = wh ? B : A;
  _Float16* __restrict__ Xh  = ws + (size_t)wh * ARR;
  _Float16* __restrict__ XTh = ws + 2 * ARR + (size_t)wh * ARR;

  __shared__ __align__(16) _Float16 tile[64][130];
  const int t = threadIdx.x;

  // phase 1: f32 -> f16, row-major swizzled write + LDS stash
#pragma unroll
  for (int it = 0; it < 4; ++it) {
    int id  = it * 256 + t;          // 0..1023 (16B chunks)
    int row = id >> 4;               // 0..63
    int ch  = id & 15;
    int grow = rt * 64 + row;
    const float* p = src + ((size_t)(b * MM + grow) * DD + ch * 8);
    float4 x0 = *(const float4*)p;
    float4 x1 = *(const float4*)(p + 4);
    f16x8 h;
    h[0] = (_Float16)x0.x; h[1] = (_Float16)x0.y; h[2] = (_Float16)x0.z; h[3] = (_Float16)x0.w;
    h[4] = (_Float16)x1.x; h[5] = (_Float16)x1.y; h[6] = (_Float16)x1.z; h[7] = (_Float16)x1.w;
    char* dst = (char*)Xh + (((size_t)(b * MM + grow)) << 8) + ((ch << 4) ^ ((row & 7) << 4));
    *(f16x8*)dst = h;
#pragma unroll
    for (int j = 0; j < 8; ++j) tile[row][ch * 8 + j] = h[j];
  }
  __syncthreads();

  // phase 2: transposed, sigma_V-permuted, swizzled write.
  // sigma_V(i): out5=i5, out4=i2, out3=i4, out2=i3, out1:0=i1:0
#pragma unroll
  for (int it = 0; it < 4; ++it) {
    int id = it * 256 + t;           // 0..1023
    int d  = id >> 3;                // 0..127
    int ch = id & 7;                 // 16B chunk within this tile's 64-kv window
    f16x8 h;
#pragma unroll
    for (int j = 0; j < 8; ++j) {
      int i = ch * 8 + j;
      int s = (i & 0x23) | ((i & 4) << 2) | ((i & 24) >> 1);
      h[j] = tile[s][d];
    }
    char* dst = (char*)XTh + (((size_t)(b * DD + d)) << 11) + (rt << 7)
              + ((ch << 4) ^ ((d & 7) << 4));
    *(f16x8*)dst = h;
  }
}

__global__ __launch_bounds__(256, 2) void attn_kernel(const _Float16* __restrict__ ws,
                                                      float* __restrict__ out) {
  // XCD-aware decomposition: blocks with same (b,dir) land on same XCD (g%8 fixed)
  const int g   = blockIdx.x;           // 0..511
  const int x   = g & 7;
  const int t2  = g >> 3;
  const int qt  = t2 & 7;               // 0..7 (128-row Q tile)
  const int p   = ((t2 >> 3) << 3) | x; // 0..63 = b + 32*dir
  const int b   = p & 31;
  const int dir = p >> 5;

  const _Float16* __restrict__ Qh  = ws + (dir ? ARR : 0);
  const _Float16* __restrict__ Kh  = ws + (dir ? 0 : ARR);
  const _Float16* __restrict__ VTh = ws + 2 * ARR + (dir ? 0 : ARR);
  float* __restrict__ outp = out + (size_t)dir * ARR;

  // double buffer: [buf][ K tile 16KB | VT tile 16KB ]
  __shared__ __align__(16) char sbuf[2][32768];

  const int tid  = threadIdx.x;
  const int w    = tid >> 6;
  const int lane = tid & 63;
  const int lrow = lane & 15;
  const int lgrp = lane >> 4;

  const int q0 = qt * 128 + w * 32 + lrow;   // qblk0; qblk1 = q0+16

  // ---- Q B-fragments (both q-blocks), loaded once from global
  f16x8 qf[2][4];
  {
    const int swz = (lrow & 7) << 4;
#pragma unroll
    for (int qb = 0; qb < 2; ++qb) {
      const char* qbase = (const char*)Qh + (((size_t)(b * MM + q0 + qb * 16)) << 8);
#pragma unroll
      for (int kc = 0; kc < 4; ++kc)
        qf[qb][kc] = *(const f16x8*)(qbase + ((kc * 64 + lgrp * 16) ^ swz));
    }
  }

  // ---- per-lane LDS byte-offset bases (swizzle folded; kc parity split)
  const int pl  = (lgrp * 16) ^ ((lrow & 3) << 4);
  const int lb6 = (lrow & 4) << 4;           // 0 or 64
  const int kE = lrow * 256 + pl + lb6;          // K reads, kc even
  const int kO = lrow * 256 + pl + (64 - lb6);   // K reads, kc odd
  const int vE = 16384 + lrow * 128 + pl + lb6;          // VT reads, kc2=0
  const int vO = 16384 + lrow * 128 + pl + (64 - lb6);   // VT reads, kc2=1

  // ---- staging source bases (per-thread)
  const char* ksrc = (const char*)Kh + (((size_t)b * MM) << 8) + (size_t)tid * 16;
  const char* vsrc = (const char*)VTh + (((size_t)b * DD) << 11)
                   + ((size_t)(tid >> 3) << 11) + (size_t)(tid & 7) * 16;

  f32x4 oacc[2][8];
#pragma unroll
  for (int qb = 0; qb < 2; ++qb)
#pragma unroll
    for (int dt = 0; dt < 8; ++dt) oacc[qb][dt] = (f32x4)0.0f;
  float mrun[2] = {-1e30f, -1e30f};
  float lrun[2] = {0.0f, 0.0f};   // per-lane partials (combined in epilogue)

  f16x8 vreg[16];   // V(t) fragments held across the iteration boundary
  f16x8 pf[2][2];   // P(t) fragments (consumed by PV in iteration t+1)

  // prologue: stage tile 0 into buf 0
  {
    char* sb = sbuf[0];
#pragma unroll
    for (int it = 0; it < 4; ++it)
      gl16(ksrc + it * 4096, sb + it * 4096 + tid * 16);
#pragma unroll
    for (int it = 0; it < 4; ++it)
      gl16(vsrc + (size_t)it * 65536, sb + 16384 + it * 4096 + tid * 16);
  }
  asm volatile("s_waitcnt vmcnt(0)" ::: "memory");
  __syncthreads();

#pragma unroll 1
  for (int t = 0; t < NTILE; ++t) {
    const char* base = sbuf[t & 1];

    // 1. issue next tile's staging early (hidden under compute)
    if (t + 1 < NTILE) {
      char* sb = sbuf[(t + 1) & 1];
      const char* kp = ksrc + (size_t)(t + 1) * 16384;
      const char* vp = vsrc + (size_t)(t + 1) * 128;
#pragma unroll
      for (int it = 0; it < 4; ++it)
        gl16(kp + it * 4096, sb + it * 4096 + tid * 16);
#pragma unroll
      for (int it = 0; it < 4; ++it)
        gl16(vp + (size_t)it * 65536, sb + 16384 + it * 4096 + tid * 16);
    }

    // 2. S^T = mfma(K, Q): rows kv (lgrp*4+r +16nt), cols q (lrow)
    //    T5: boost this block's priority while in the MFMA cluster — the other
    //    (independent) block on the CU is typically in its staging/softmax phase.
    f32x4 sc[2][4];
#pragma unroll
    for (int qb = 0; qb < 2; ++qb)
#pragma unroll
      for (int nt = 0; nt < 4; ++nt) sc[qb][nt] = (f32x4)0.0f;
    __builtin_amdgcn_s_setprio(1);
#pragma unroll
    for (int nt = 0; nt < 4; ++nt) {
#pragma unroll
      for (int kc = 0; kc < 4; ++kc) {
        const int off = ((kc & 1) ? kO + (kc - 1) * 64 : kE + kc * 64) + nt * 4096;
        f16x8 kf = *(const f16x8*)(base + off);
        sc[0][nt] = __builtin_amdgcn_mfma_f32_16x16x32_f16(kf, qf[0][kc], sc[0][nt], 0, 0, 0);
        sc[1][nt] = __builtin_amdgcn_mfma_f32_16x16x32_f16(kf, qf[1][kc], sc[1][nt], 0, 0, 0);
      }
    }
    __builtin_amdgcn_s_setprio(0);

    // 3. PV(t-1): register-only MFMA stream (independent of QK above)
    if (t > 0) {
      __builtin_amdgcn_s_setprio(1);
#pragma unroll
      for (int dt = 0; dt < 8; ++dt) {
        oacc[0][dt] = __builtin_amdgcn_mfma_f32_16x16x32_f16(vreg[dt * 2 + 0], pf[0][0], oacc[0][dt], 0, 0, 0);
        oacc[0][dt] = __builtin_amdgcn_mfma_f32_16x16x32_f16(vreg[dt * 2 + 1], pf[0][1], oacc[0][dt], 0, 0, 0);
        oacc[1][dt] = __builtin_amdgcn_mfma_f32_16x16x32_f16(vreg[dt * 2 + 0], pf[1][0], oacc[1][dt], 0, 0, 0);
        oacc[1][dt] = __builtin_amdgcn_mfma_f32_16x16x32_f16(vreg[dt * 2 + 1], pf[1][1], oacc[1][dt], 0, 0, 0);
      }
      __builtin_amdgcn_s_setprio(0);
    }

    // 4. V(t) LDS -> registers (consumed by PV next iteration)
#pragma unroll
    for (int dt = 0; dt < 8; ++dt) {
      vreg[dt * 2 + 0] = *(const f16x8*)(base + vE + dt * 2048);
      vreg[dt * 2 + 1] = *(const f16x8*)(base + vO + dt * 2048);
    }

    // 5. softmax(t): in-lane max check; cross-lane only on rare trigger
    float mx[2];
#pragma unroll
    for (int qb = 0; qb < 2; ++qb) {
      float a0 = fmaxf(fmaxf(sc[qb][0][0], sc[qb][0][1]), fmaxf(sc[qb][0][2], sc[qb][0][3]));
      float a1 = fmaxf(fmaxf(sc[qb][1][0], sc[qb][1][1]), fmaxf(sc[qb][1][2], sc[qb][1][3]));
      float a2 = fmaxf(fmaxf(sc[qb][2][0], sc[qb][2][1]), fmaxf(sc[qb][2][2], sc[qb][2][3]));
      float a3 = fmaxf(fmaxf(sc[qb][3][0], sc[qb][3][1]), fmaxf(sc[qb][3][2], sc[qb][3][3]));
      mx[qb] = fmaxf(fmaxf(a0, a1), fmaxf(a2, a3));
    }
    bool need = (mx[0] > mrun[0] + RTHR) || (mx[1] > mrun[1] + RTHR);
    if (__any(need)) {
#pragma unroll
      for (int qb = 0; qb < 2; ++qb) {
        float cm = mx[qb];
        cm = fmaxf(cm, __shfl_xor(cm, 16));
        cm = fmaxf(cm, __shfl_xor(cm, 32));
        float mnew = fmaxf(mrun[qb], cm);
        float scale = fexp2((mrun[qb] - mnew) * LOG2E);
        lrun[qb] *= scale;
#pragma unroll
        for (int dt = 0; dt < 8; ++dt) oacc[qb][dt] *= scale;
        mrun[qb] = mnew;
      }
    }

    // 6. P = exp(S - m) in-lane, pack to f16 B-fragments (sigma_V aligned)
#pragma unroll
    for (int qb = 0; qb < 2; ++qb) {
      union { fp16x2 h[8]; f16x8 v[2]; } u;
      float ps = 0.0f;
      const float nml = -mrun[qb] * LOG2E;
#pragma unroll
      for (int nt = 0; nt < 4; ++nt) {
        float p0 = fexp2(fmaf(sc[qb][nt][0], LOG2E, nml));
        float p1 = fexp2(fmaf(sc[qb][nt][1], LOG2E, nml));
        float p2 = fexp2(fmaf(sc[qb][nt][2], LOG2E, nml));
        float p3 = fexp2(fmaf(sc[qb][nt][3], LOG2E, nml));
        ps += (p0 + p1) + (p2 + p3);
        u.h[nt * 2 + 0] = __builtin_amdgcn_cvt_pkrtz(p0, p1);
        u.h[nt * 2 + 1] = __builtin_amdgcn_cvt_pkrtz(p2, p3);
      }
      lrun[qb] += ps;
      pf[qb][0] = u.v[0];
      pf[qb][1] = u.v[1];
    }

    // 7. staging of t+1 landed (issued ~2000cy ago); drain + barrier
    asm volatile("s_waitcnt vmcnt(0)" ::: "memory");
    __syncthreads();
  }

  // ---- drain: PV(NTILE-1)
#pragma unroll
  for (int dt = 0; dt < 8; ++dt) {
    oacc[0][dt] = __builtin_amdgcn_mfma_f32_16x16x32_f16(vreg[dt * 2 + 0], pf[0][0], oacc[0][dt], 0, 0, 0);
    oacc[0][dt] = __builtin_amdgcn_mfma_f32_16x16x32_f16(vreg[dt * 2 + 1], pf[0][1], oacc[0][dt], 0, 0, 0);
    oacc[1][dt] = __builtin_amdgcn_mfma_f32_16x16x32_f16(vreg[dt * 2 + 0], pf[1][0], oacc[1][dt], 0, 0, 0);
    oacc[1][dt] = __builtin_amdgcn_mfma_f32_16x16x32_f16(vreg[dt * 2 + 1], pf[1][1], oacc[1][dt], 0, 0, 0);
  }

  // ---- epilogue: combine per-lane l, normalize, store f32x4
#pragma unroll
  for (int qb = 0; qb < 2; ++qb) {
    float l = lrun[qb];
    l += __shfl_xor(l, 16);
    l += __shfl_xor(l, 32);
    float inv = __builtin_amdgcn_rcpf(l);
    float* op = outp + ((size_t)(b * MM + q0 + qb * 16)) * DD + lgrp * 4;
#pragma unroll
    for (int dt = 0; dt < 8; ++dt) {
      f32x4 v = oacc[qb][dt] * inv;
      *(f32x4*)(op + dt * 16) = v;
    }
  }
}

extern "C" void kernel_launch(void* const* d_in, const int* in_sizes, int n_in,
                              void* d_out, int out_size, void* d_ws, size_t ws_size,
                              hipStream_t stream) {
  const float* A = (const float*)d_in[0];
  const float* B = (const float*)d_in[1];
  float* out = (float*)d_out;
  if (ws_size < 4 * ARR * sizeof(_Float16)) return;  // need 33.6 MB scratch
  _Float16* ws = (_Float16*)d_ws;

  dim3 g1(16, 32, 2);
  prep_kernel<<<g1, dim3(256, 1, 1), 0, stream>>>(A, B, ws);
  dim3 g2(512, 1, 1);
  attn_kernel<<<g2, dim3(256, 1, 1), 0, stream>>>(ws, out);
}